// Round 10
// baseline (462.852 us; speedup 1.0000x reference)
//
#include <hip/hip_runtime.h>

// out[b,f,t] = sum_{c,dt} exp(-g*x[b,c,t+dt])[x!=0] * w[c*48+dt*16+f]
// im2col GEMM, M=t (98/batch), N=f (16), K=(c,dt). MFMA bf16 16x16x32.
// ET[t][c] layout in LDS (pitch 72 ushorts = 144B, 16B-aligned rows):
//   A-fragment = ONE ds_read_b128 (8 consecutive c at fixed t).
// Staging keeps r5's COALESCED global mapping (thread i -> contiguous
// float4 = 4 t of one c) and writes the 4 values transposed (ds_write_b16;
// ~700 bank-cycles/block, measured secondary in r6). No LDS zero pass:
// ET rows t>=100 are garbage but only feed masked D-rows m>=98; tail-chunk
// channels zero-filled at load; W zero-filled explicitly.
#define BB     64
#define NNCH   10000
#define TOUT   98
#define FF     16
#define CPB    64                 // channels per block
#define NCHUNK 157                // ceil(10000/64); grid = 64*157
#define ETP    72                 // ET pitch (ushort): 64 data + 8 pad
#define ETROWS 116                // trow up to 113 read
#define WP     200                // W row pitch (ushort)

typedef __attribute__((ext_vector_type(8))) short s8v;   // 8 bf16
typedef __attribute__((ext_vector_type(4))) float f4v;   // 4 fp32 acc

__device__ __forceinline__ ushort bf_rne(float v) {
    unsigned b = __float_as_uint(v);
    return (ushort)((b + 0x7FFFu + ((b >> 16) & 1u)) >> 16);
}

__global__ __launch_bounds__(256) void tgcnn_mfma(
    const float* __restrict__ x,      // (B, NN, T=100) fp32
    const float* __restrict__ w,      // (NN*3, 16) fp32: c*48 + dt*16 + f
    const float* __restrict__ gammat, // fp32 scalar
    float* __restrict__ out)          // (B, F, 1, TOUT) fp32, pre-zeroed
{
    __shared__ __align__(16) ushort ET[ETROWS][ETP];  // 16704 B
    __shared__ __align__(16) ushort W[FF][WP];        // 6400 B

    const int tid = threadIdx.x;
    const int bid = blockIdx.x;
    const int b   = bid / NCHUNK;
    const int cs  = bid - b * NCHUNK;
    const int cbase = cs * CPB;

    const float gt    = gammat[0];
    const float gamma = 10.0f / (1.0f + __expf(-gt));
    const float kk    = -gamma * 1.4426950408889634f;   // exp(-g*x)=exp2(kk*x)

    // ---- stage E: coalesced float4 (4 t of one c) -> exp -> 4 transposed
    // ds_write_b16 into ET[t][c] ----
    const float4* x4 = (const float4*)x;
    for (int i = tid; i < CPB * 25; i += 256) {
        const int cl = i / 25, q = i - cl * 25;
        const int c  = cbase + cl;
        float4 v = make_float4(0.f, 0.f, 0.f, 0.f);
        if (c < NNCH) v = x4[((size_t)b * NNCH + c) * 25 + q];
        const int t0 = q * 4;
        ET[t0 + 0][cl] = (v.x != 0.f) ? bf_rne(exp2f(kk * v.x)) : 0;
        ET[t0 + 1][cl] = (v.y != 0.f) ? bf_rne(exp2f(kk * v.y)) : 0;
        ET[t0 + 2][cl] = (v.z != 0.f) ? bf_rne(exp2f(kk * v.z)) : 0;
        ET[t0 + 3][cl] = (v.w != 0.f) ? bf_rne(exp2f(kk * v.w)) : 0;
    }

    // ---- stage W: w[c*48+dt*16+f] -> W[f][dt*64+cl], zero-filled tail ----
    const float4* wg4 = (const float4*)w;
    for (int i = tid; i < CPB * 12; i += 256) {
        const int cl = i / 12, r = i - cl * 12;
        const int c  = cbase + cl;
        float4 wv = make_float4(0.f, 0.f, 0.f, 0.f);
        if (c < NNCH) wv = wg4[(size_t)c * 12 + r];
        const int dt = r >> 2, fq = (r & 3) * 4, kp = dt * CPB + cl;
        W[fq + 0][kp] = bf_rne(wv.x);
        W[fq + 1][kp] = bf_rne(wv.y);
        W[fq + 2][kp] = bf_rne(wv.z);
        W[fq + 3][kp] = bf_rne(wv.w);
    }
    __syncthreads();

    // ---- MFMA: 7 t-tiles; wave owns {wave, wave+4} (wave 3: tile 3 only)
    const int wave = tid >> 6, lane = tid & 63;
    const int tcol = lane & 15;        // A row (t in tile) / B,D col (f)
    const int kb   = lane >> 4;        // k-octet
    const int tile0 = wave, tile1 = wave + 4;
    const bool two  = (tile1 < 7);

    f4v acc0 = {0.f, 0.f, 0.f, 0.f};
    f4v acc1 = {0.f, 0.f, 0.f, 0.f};

    #pragma unroll
    for (int ks = 0; ks < 6; ++ks) {
        const int dt = ks >> 1;
        const int cb = (ks & 1) * 32 + kb * 8;

        const s8v bfrag = *(const s8v*)&W[tcol][ks * 32 + kb * 8];

        const int trow0 = tile0 * 16 + tcol + dt;
        const s8v a0 = *(const s8v*)&ET[trow0][cb];   // one ds_read_b128
        acc0 = __builtin_amdgcn_mfma_f32_16x16x32_bf16(a0, bfrag, acc0, 0, 0, 0);

        if (two) {
            const int trow1 = tile1 * 16 + tcol + dt;
            const s8v a1 = *(const s8v*)&ET[trow1][cb];
            acc1 = __builtin_amdgcn_mfma_f32_16x16x32_bf16(a1, bfrag, acc1, 0, 0, 0);
        }
    }

    // ---- epilogue: atomics into out (B,F,1,T); D: col=f, row=(lane>>4)*4+r
    float* ob = out + (size_t)b * FF * TOUT;
    const int f = lane & 15;
    const int rbase = (lane >> 4) * 4;
    #pragma unroll
    for (int r = 0; r < 4; ++r) {
        const int m = tile0 * 16 + rbase + r;
        if (m < TOUT) atomicAdd(&ob[f * TOUT + m], acc0[r]);
    }
    if (two) {
        #pragma unroll
        for (int r = 0; r < 4; ++r) {
            const int m = tile1 * 16 + rbase + r;
            if (m < TOUT) atomicAdd(&ob[f * TOUT + m], acc1[r]);
        }
    }
}

extern "C" void kernel_launch(void* const* d_in, const int* in_sizes, int n_in,
                              void* d_out, int out_size, void* d_ws, size_t ws_size,
                              hipStream_t stream) {
    const float* x = (const float*)d_in[0];
    const float* w = (const float*)d_in[1];
    const float* g = (const float*)d_in[2];

    hipMemsetAsync(d_out, 0, (size_t)out_size * sizeof(float), stream);
    tgcnn_mfma<<<BB * NCHUNK, 256, 0, stream>>>(x, w, g, (float*)d_out);
}

// Round 11
// 89.823 us; speedup vs baseline: 5.1529x; 5.1529x over previous
//
#include <hip/hip_runtime.h>

// out[b,f,t] = sum_{c,dt} exp(-g*x[b,c,t+dt])[x!=0] * w[c*48+dt*16+f]
// im2col GEMM, M=t (98/batch), N=f (16), K=(c,dt). MFMA bf16 16x16x32.
// Key lesson r5/r9 vs r6/r7/r10: atomics to d_out are ~25-70x slower than to
// d_ws (fine-grained memory), and every global atomic costs ~20B HBM
// write-through. This version has ZERO global atomics: each block owns an
// exclusive ws slice (plain stores), finalize reduces nco slices.
// E layout [c][t] with EP=106 (53 words/row): MFMA gathers are 2-way = free
// (8kb term spans {0,8,16,24}, tcol spans 8 consecutive), staging ~2-3-way.
#define BB     64
#define NNCH   10000
#define TOUT   98
#define FF     16
#define CPB    64                 // channels per chunk
#define NCHUNK 157                // ceil(10000/64)
#define EP     106                // E row pitch (ushort), stride 53 words
#define WP     200                // W row pitch (ushort)
#define ACCN   (TOUT * FF)        // 1568

typedef __attribute__((ext_vector_type(8))) short s8v;   // 8 bf16
typedef __attribute__((ext_vector_type(4))) float f4v;   // 4 fp32 acc

__device__ __forceinline__ ushort bf_rne(float v) {
    unsigned b = __float_as_uint(v);
    return (ushort)((b + 0x7FFFu + ((b >> 16) & 1u)) >> 16);
}

__global__ __launch_bounds__(256) void tgcnn_mfma(
    const float* __restrict__ x,      // (B, NN, T=100) fp32
    const float* __restrict__ w,      // (NN*3, 16) fp32: c*48 + dt*16 + f
    const float* __restrict__ gammat, // fp32 scalar
    float* __restrict__ ws,           // nco x (B, TOUT, F) fp32 (excl. slices)
    int nco, int ch)
{
    __shared__ __align__(16) ushort E[CPB + 1][EP];  // +1 row: tile-6 tail pad
    __shared__ __align__(16) ushort W[FF][WP];

    const int tid = threadIdx.x;
    const int bid = blockIdx.x;
    const int b   = bid / nco;
    const int co  = bid - b * nco;

    const float gt    = gammat[0];
    const float gamma = 10.0f / (1.0f + __expf(-gt));
    const float kk    = -gamma * 1.4426950408889634f;   // exp(-g*x)=exp2(kk*x)

    const int wave = tid >> 6, lane = tid & 63;
    const int tcol = lane & 15;        // A row (t in tile) / B,D col (f)
    const int kb   = lane >> 4;        // k-octet
    const int tile0 = wave, tile1 = wave + 4;
    const bool two  = (tile1 < 7);

    f4v acc0 = {0.f, 0.f, 0.f, 0.f};
    f4v acc1 = {0.f, 0.f, 0.f, 0.f};

    const float4* x4  = (const float4*)x;
    const float4* wg4 = (const float4*)w;

    for (int kc = 0; kc < ch; ++kc) {
        const int cs = co * ch + kc;
        if (cs >= NCHUNK) break;
        const int cbase = cs * CPB;

        if (kc) __syncthreads();   // protect LDS reuse across chunks

        // stage E: coalesced float4 (4 t of one c) -> exp -> 2x b32 writes
        for (int i = tid; i < CPB * 25; i += 256) {
            const int cl = i / 25, q = i - cl * 25;
            const int c  = cbase + cl;
            float4 v = make_float4(0.f, 0.f, 0.f, 0.f);
            if (c < NNCH) v = x4[((size_t)b * NNCH + c) * 25 + q];
            const unsigned e0 = (v.x != 0.f) ? bf_rne(exp2f(kk * v.x)) : 0;
            const unsigned e1 = (v.y != 0.f) ? bf_rne(exp2f(kk * v.y)) : 0;
            const unsigned e2 = (v.z != 0.f) ? bf_rne(exp2f(kk * v.z)) : 0;
            const unsigned e3 = (v.w != 0.f) ? bf_rne(exp2f(kk * v.w)) : 0;
            *(unsigned*)&E[cl][q * 4 + 0] = e0 | (e1 << 16);
            *(unsigned*)&E[cl][q * 4 + 2] = e2 | (e3 << 16);
        }

        // stage W: w[c*48+dt*16+f] -> W[f][dt*64+cl], zero-filled tail
        for (int i = tid; i < CPB * 12; i += 256) {
            const int cl = i / 12, r = i - cl * 12;
            const int c  = cbase + cl;
            float4 wv = make_float4(0.f, 0.f, 0.f, 0.f);
            if (c < NNCH) wv = wg4[(size_t)c * 12 + r];
            const int dt = r >> 2, fq = (r & 3) * 4, kp = dt * CPB + cl;
            W[fq + 0][kp] = bf_rne(wv.x);
            W[fq + 1][kp] = bf_rne(wv.y);
            W[fq + 2][kp] = bf_rne(wv.z);
            W[fq + 3][kp] = bf_rne(wv.w);
        }
        __syncthreads();

        // MFMA: 7 t-tiles; wave owns {wave, wave+4} (wave 3: tile 3 only)
        #pragma unroll
        for (int ks = 0; ks < 6; ++ks) {
            const int dt = ks >> 1;
            const int cb = (ks & 1) * 32 + kb * 8;

            const s8v bfrag = *(const s8v*)&W[tcol][ks * 32 + kb * 8];

            {
                const int trow = tile0 * 16 + tcol + dt;
                s8v afrag;
                #pragma unroll
                for (int j = 0; j < 8; ++j) afrag[j] = (short)E[cb + j][trow];
                acc0 = __builtin_amdgcn_mfma_f32_16x16x32_bf16(afrag, bfrag, acc0, 0, 0, 0);
            }
            if (two) {
                const int trow = tile1 * 16 + tcol + dt;
                s8v afrag;
                #pragma unroll
                for (int j = 0; j < 8; ++j) afrag[j] = (short)E[cb + j][trow];
                acc1 = __builtin_amdgcn_mfma_f32_16x16x32_bf16(afrag, bfrag, acc1, 0, 0, 0);
            }
        }
    }

    // epilogue: PLAIN stores into this block's exclusive ws slice.
    // tiles 0..6 x rbase x f cover every (m<98, f) exactly once.
    float* wsb = ws + ((size_t)co * BB + b) * ACCN;
    const int f = lane & 15;
    const int rbase = (lane >> 4) * 4;
    #pragma unroll
    for (int r = 0; r < 4; ++r) {
        const int m = tile0 * 16 + rbase + r;
        if (m < TOUT) wsb[m * FF + f] = acc0[r];
    }
    if (two) {
        #pragma unroll
        for (int r = 0; r < 4; ++r) {
            const int m = tile1 * 16 + rbase + r;
            if (m < TOUT) wsb[m * FF + f] = acc1[r];
        }
    }
}

__global__ __launch_bounds__(256) void tgcnn_finalize(
    const float* __restrict__ ws, float* __restrict__ out, int nco)
{
    int i = blockIdx.x * 256 + threadIdx.x;
    if (i >= BB * FF * TOUT) return;
    int t = i % TOUT;
    int f = (i / TOUT) & (FF - 1);
    int b = i / (FF * TOUT);
    float s = 0.f;
    for (int co = 0; co < nco; ++co)
        s += ws[((size_t)co * BB + b) * ACCN + t * FF + f];
    out[i] = s;                        // (B,T,F) -> (B,F,1,T)
}

extern "C" void kernel_launch(void* const* d_in, const int* in_sizes, int n_in,
                              void* d_out, int out_size, void* d_ws, size_t ws_size,
                              hipStream_t stream) {
    const float* x = (const float*)d_in[0];
    const float* w = (const float*)d_in[1];
    const float* g = (const float*)d_in[2];
    float* ws = (float*)d_ws;

    const size_t slot = (size_t)BB * ACCN * sizeof(float);   // 401 KB
    int navail = (int)(ws_size / slot);
    int nco = navail < 1 ? 1 : (navail > 40 ? 40 : navail);
    int ch  = (NCHUNK + nco - 1) / nco;

    tgcnn_mfma<<<BB * nco, 256, 0, stream>>>(x, w, g, ws, nco, ch);
    tgcnn_finalize<<<(BB * FF * TOUT + 255) / 256, 256, 0, stream>>>(
        ws, (float*)d_out, nco);
}